// Round 1
// baseline (3161.010 us; speedup 1.0000x reference)
//
#include <hip/hip_runtime.h>
#include <math.h>

#define NN 100000
#define NE 1600000

// ---------------- degree / norm ----------------
__global__ void degree_kernel(const int* __restrict__ dst, float* __restrict__ deg, int E) {
    int e = blockIdx.x * blockDim.x + threadIdx.x;
    if (e < E) atomicAdd(&deg[dst[e]], 1.0f);
}

__global__ void norm_kernel(float* __restrict__ deg_norm, int n) {
    int i = blockIdx.x * blockDim.x + threadIdx.x;
    if (i < n) deg_norm[i] = rsqrtf(fmaxf(deg_norm[i], 1.0f));
}

// ---------------- edge scatter: agg[dst] += h[src]*norm[src] ----------------
// One thread per (edge, feature). Lanes cover one row -> coalesced gather and
// coalesced atomic burst.
template<int D>
__global__ void scatter_kernel(const float* __restrict__ h,
                               const float* __restrict__ nrm,
                               const int* __restrict__ src,
                               const int* __restrict__ dst,
                               float* __restrict__ agg, int E) {
    long long t = (long long)blockIdx.x * blockDim.x + threadIdx.x;
    int e = (int)(t / D);
    int f = (int)(t % D);
    if (e >= E) return;
    int s = src[e];
    int d = dst[e];
    float v = h[(long long)s * D + f] * nrm[s];
    atomicAdd(&agg[(long long)d * D + f], v);
}

// ---------------- node apply: out = act(norm * (agg @ W^T) + b) ----------------
// ACT: 0 = identity, 1 = relu, 2 = sigmoid. W is [OUT][IN] row-major.
// Weights staged to LDS transposed [k][o] so lanes (varying o) read consecutive banks.
template<int IN, int OUT, int ACT>
__global__ void apply_kernel(const float* __restrict__ agg,
                             const float* __restrict__ nrm,
                             const float* __restrict__ W,
                             const float* __restrict__ b,
                             float* __restrict__ out, int n) {
    __shared__ float Wt[IN * OUT];
    __shared__ float bs[OUT];
    for (int i = threadIdx.x; i < IN * OUT; i += blockDim.x) {
        int o = i / IN, k = i % IN;
        Wt[k * OUT + o] = W[i];
    }
    if (threadIdx.x < OUT) bs[threadIdx.x] = b[threadIdx.x];
    __syncthreads();
    int t = blockIdx.x * blockDim.x + threadIdx.x;
    int node = t / OUT, o = t % OUT;
    if (node >= n) return;
    const float* arow = agg + (long long)node * IN;
    float acc = 0.0f;
#pragma unroll
    for (int k = 0; k < IN; ++k) acc += arow[k] * Wt[k * OUT + o];
    acc = acc * nrm[node] + bs[o];
    if (ACT == 1) acc = fmaxf(acc, 0.0f);
    if (ACT == 2) acc = 1.0f / (1.0f + expf(-acc));
    out[(long long)node * OUT + o] = acc;
}

// mu / log_var share one aggregation; dual-headed projection (32+32 outputs).
__global__ void apply_mulv_kernel(const float* __restrict__ agg,
                                  const float* __restrict__ nrm,
                                  const float* __restrict__ W31, const float* __restrict__ b31,
                                  const float* __restrict__ W32, const float* __restrict__ b32,
                                  float* __restrict__ mu, float* __restrict__ lv, int n) {
    __shared__ float Wt[64 * 64];  // [k][o]: o<32 -> W31 row o, o>=32 -> W32 row o-32
    __shared__ float bs[64];
    for (int i = threadIdx.x; i < 32 * 64; i += blockDim.x) {
        int o = i / 64, k = i % 64;   // W31/W32 are [32][64]
        Wt[k * 64 + o]      = W31[i];
        Wt[k * 64 + o + 32] = W32[i];
    }
    if (threadIdx.x < 32) {
        bs[threadIdx.x]      = b31[threadIdx.x];
        bs[threadIdx.x + 32] = b32[threadIdx.x];
    }
    __syncthreads();
    int t = blockIdx.x * blockDim.x + threadIdx.x;
    int node = t / 64, o = t % 64;
    if (node >= n) return;
    const float* arow = agg + (long long)node * 64;
    float acc = 0.0f;
#pragma unroll
    for (int k = 0; k < 64; ++k) acc += arow[k] * Wt[k * 64 + o];
    acc = acc * nrm[node] + bs[o];
    if (o < 32) mu[(long long)node * 32 + o] = acc;
    else        lv[(long long)node * 32 + (o - 32)] = acc;
}

// z = eps * exp(0.5*log_var) + mu   (flat over N*32)
__global__ void z_kernel(const float* __restrict__ eps,
                         const float* __restrict__ mu,
                         const float* __restrict__ lv,
                         float* __restrict__ z, int n) {
    int t = blockIdx.x * blockDim.x + threadIdx.x;
    if (t < n) z[t] = eps[t] * expf(0.5f * lv[t]) + mu[t];
}

extern "C" void kernel_launch(void* const* d_in, const int* in_sizes, int n_in,
                              void* d_out, int out_size, void* d_ws, size_t ws_size,
                              hipStream_t stream) {
    const float* x    = (const float*)d_in[0];
    const int*   esrc = (const int*)d_in[1];
    const int*   edst = (const int*)d_in[2];
    const float* eps  = (const float*)d_in[3];
    const float* W1  = (const float*)d_in[4];  const float* b1  = (const float*)d_in[5];
    const float* W2  = (const float*)d_in[6];  const float* b2  = (const float*)d_in[7];
    const float* W31 = (const float*)d_in[8];  const float* b31 = (const float*)d_in[9];
    const float* W32 = (const float*)d_in[10]; const float* b32 = (const float*)d_in[11];
    const float* W4  = (const float*)d_in[12]; const float* b4  = (const float*)d_in[13];
    const float* W5  = (const float*)d_in[14]; const float* b5  = (const float*)d_in[15];
    const float* W6  = (const float*)d_in[16]; const float* b6  = (const float*)d_in[17];

    const int N = NN, E = NE;
    float* out   = (float*)d_out;
    float* recon = out;                    // N*64
    float* mu    = out + (size_t)N * 64;   // N*32
    float* lv    = mu  + (size_t)N * 32;   // N*32

    float* nrm = (float*)d_ws;             // N
    float* agg = nrm + N;                  // N*64
    float* hA  = agg + (size_t)N * 64;     // N*64
    float* hB  = hA  + (size_t)N * 64;     // N*64

    const int SB = 256;
    const int egrid   = (E + SB - 1) / SB;
    const int sgrid64 = (E * 64 + SB - 1) / SB;   // 102.4M threads, fits int
    const int sgrid32 = (E * 32 + SB - 1) / SB;
    const int agrid   = (N * 64 + SB - 1) / SB;
    const int zgrid   = (N * 32 + SB - 1) / SB;

    // degree -> norm (in place in nrm)
    hipMemsetAsync(nrm, 0, (size_t)N * sizeof(float), stream);
    degree_kernel<<<egrid, SB, 0, stream>>>(edst, nrm, E);
    norm_kernel<<<(N + SB - 1) / SB, SB, 0, stream>>>(nrm, N);

    // L1: x -> hA (relu)
    hipMemsetAsync(agg, 0, (size_t)N * 64 * sizeof(float), stream);
    scatter_kernel<64><<<sgrid64, SB, 0, stream>>>(x, nrm, esrc, edst, agg, E);
    apply_kernel<64, 64, 1><<<agrid, SB, 0, stream>>>(agg, nrm, W1, b1, hA, N);

    // L2: hA -> hB (relu)
    hipMemsetAsync(agg, 0, (size_t)N * 64 * sizeof(float), stream);
    scatter_kernel<64><<<sgrid64, SB, 0, stream>>>(hA, nrm, esrc, edst, agg, E);
    apply_kernel<64, 64, 1><<<agrid, SB, 0, stream>>>(agg, nrm, W2, b2, hB, N);

    // L3: hB -> mu, lv (shared aggregation, identity act)
    hipMemsetAsync(agg, 0, (size_t)N * 64 * sizeof(float), stream);
    scatter_kernel<64><<<sgrid64, SB, 0, stream>>>(hB, nrm, esrc, edst, agg, E);
    apply_mulv_kernel<<<agrid, SB, 0, stream>>>(agg, nrm, W31, b31, W32, b32, mu, lv, N);

    // z = eps*exp(0.5*lv)+mu  -> packed [N,32] in hA
    z_kernel<<<zgrid, SB, 0, stream>>>(eps, mu, lv, hA, N * 32);

    // L4: z(hA, d=32) -> hB (relu)
    hipMemsetAsync(agg, 0, (size_t)N * 32 * sizeof(float), stream);
    scatter_kernel<32><<<sgrid32, SB, 0, stream>>>(hA, nrm, esrc, edst, agg, E);
    apply_kernel<32, 64, 1><<<agrid, SB, 0, stream>>>(agg, nrm, W4, b4, hB, N);

    // L5: hB -> hA (relu)
    hipMemsetAsync(agg, 0, (size_t)N * 64 * sizeof(float), stream);
    scatter_kernel<64><<<sgrid64, SB, 0, stream>>>(hB, nrm, esrc, edst, agg, E);
    apply_kernel<64, 64, 1><<<agrid, SB, 0, stream>>>(agg, nrm, W5, b5, hA, N);

    // L6: hA -> recon (sigmoid)
    hipMemsetAsync(agg, 0, (size_t)N * 64 * sizeof(float), stream);
    scatter_kernel<64><<<sgrid64, SB, 0, stream>>>(hA, nrm, esrc, edst, agg, E);
    apply_kernel<64, 64, 2><<<agrid, SB, 0, stream>>>(agg, nrm, W6, b6, recon, N);
}

// Round 2
// 977.191 us; speedup vs baseline: 3.2348x; 3.2348x over previous
//
#include <hip/hip_runtime.h>
#include <math.h>

#define NN 100000
#define NE 1600000
#define NB_SCAN ((NN + 255) / 256)   // 391 scan blocks

// ---------------- CSR build ----------------
__global__ void degree_int_kernel(const int* __restrict__ dst, int* __restrict__ deg, int E) {
    int e = blockIdx.x * blockDim.x + threadIdx.x;
    if (e < E) atomicAdd(&deg[dst[e]], 1);
}

__global__ void norm_from_deg_kernel(const int* __restrict__ deg, float* __restrict__ nrm, int n) {
    int i = blockIdx.x * blockDim.x + threadIdx.x;
    if (i < n) nrm[i] = rsqrtf(fmaxf((float)deg[i], 1.0f));
}

// per-256-block inclusive scan of deg -> incl, block sums -> bsums
__global__ void block_scan_kernel(const int* __restrict__ deg, int* __restrict__ incl,
                                  int* __restrict__ bsums, int n) {
    __shared__ int s[256];
    int tid = threadIdx.x;
    int i = blockIdx.x * 256 + tid;
    s[tid] = (i < n) ? deg[i] : 0;
    __syncthreads();
    for (int off = 1; off < 256; off <<= 1) {
        int t = (tid >= off) ? s[tid - off] : 0;
        __syncthreads();
        s[tid] += t;
        __syncthreads();
    }
    if (i < n) incl[i] = s[tid];
    if (tid == 255) bsums[blockIdx.x] = s[255];
}

// single-block inclusive scan of the 391 block sums (padded to 512)
__global__ void scan_sums_kernel(int* __restrict__ bsums, int nb) {
    __shared__ int s[512];
    int tid = threadIdx.x;
    s[tid] = (tid < nb) ? bsums[tid] : 0;
    __syncthreads();
    for (int off = 1; off < 512; off <<= 1) {
        int t = (tid >= off) ? s[tid - off] : 0;
        __syncthreads();
        s[tid] += t;
        __syncthreads();
    }
    if (tid < nb) bsums[tid] = s[tid];
}

// exclusive row_start + cursor copy
__global__ void finalize_scan_kernel(const int* __restrict__ incl, const int* __restrict__ deg,
                                     const int* __restrict__ bsums,
                                     int* __restrict__ row_start, int* __restrict__ cursor,
                                     int n, int E) {
    int i = blockIdx.x * blockDim.x + threadIdx.x;
    if (i < n) {
        int b = i >> 8;
        int off = (b > 0) ? bsums[b - 1] : 0;
        int ex = off + incl[i] - deg[i];
        row_start[i] = ex;
        cursor[i] = ex;
        if (i == 0) row_start[n] = E;
    }
}

__global__ void fill_csr_kernel(const int* __restrict__ src, const int* __restrict__ dst,
                                int* __restrict__ cursor, int* __restrict__ csr, int E) {
    int e = blockIdx.x * blockDim.x + threadIdx.x;
    if (e < E) {
        int pos = atomicAdd(&cursor[dst[e]], 1);
        csr[pos] = src[e];
    }
}

// x' = x * nrm[node]  (pre-scale input features; D = 64)
__global__ void scale_x_kernel(const float* __restrict__ x, const float* __restrict__ nrm,
                               float* __restrict__ xs, int total) {
    int i = blockIdx.x * blockDim.x + threadIdx.x;
    if (i < total) xs[i] = x[i] * nrm[i >> 6];
}

// z' = (eps * exp(0.5*lv) + mu) * nrm[node]   (D = 32, pre-scaled for layer 4)
__global__ void z_scaled_kernel(const float* __restrict__ eps, const float* __restrict__ mu,
                                const float* __restrict__ lv, const float* __restrict__ nrm,
                                float* __restrict__ zs, int total) {
    int i = blockIdx.x * blockDim.x + threadIdx.x;
    if (i < total) zs[i] = (eps[i] * expf(0.5f * lv[i]) + mu[i]) * nrm[i >> 5];
}

// ---------------- fused gather + linear + act ----------------
// One wave per node (4 nodes / 256-thread block; N divisible by 4).
// h is PRE-SCALED by nrm[src], so gather is a pure row sum.
// out = act(nrm_dst * (agg @ W^T) + b), optionally re-scaled by nrm_dst for the
// next layer's gather (SCALE). DUAL: two 32-wide heads (mu | lv) sharing agg.
// ACT: 0 ident, 1 relu, 2 sigmoid.
template<int IN, int ACT, bool SCALE, bool DUAL>
__global__ __launch_bounds__(256) void gcn_fused_kernel(
        const float* __restrict__ h,
        const float* __restrict__ nrm,
        const int* __restrict__ row_start,
        const int* __restrict__ csr,
        const float* __restrict__ Wa, const float* __restrict__ ba,
        const float* __restrict__ Wb, const float* __restrict__ bb,
        float* __restrict__ out, float* __restrict__ out2) {
    constexpr int OUT = 64;
    __shared__ float Wt[IN * 65];   // [k][o], padded stride 65 -> conflict-free both ways
    __shared__ float bs[OUT];
    __shared__ float aggS[4][IN];

    int tid = threadIdx.x;
    if (DUAL) {
        for (int i = tid; i < 32 * 64; i += 256) {   // Wa/Wb are [32][64]
            int o = i >> 6, k = i & 63;
            Wt[k * 65 + o]      = Wa[i];
            Wt[k * 65 + o + 32] = Wb[i];
        }
        if (tid < 32) { bs[tid] = ba[tid]; bs[tid + 32] = bb[tid]; }
    } else {
        for (int i = tid; i < OUT * IN; i += 256) {  // Wa is [64][IN]
            int o = i / IN, k = i % IN;
            Wt[k * 65 + o] = Wa[i];
        }
        if (tid < OUT) bs[tid] = ba[tid];
    }

    int wave = tid >> 6, lane = tid & 63;
    int node = blockIdx.x * 4 + wave;
    int rs = row_start[node], re = row_start[node + 1];

    float a0 = 0.f, a1 = 0.f, a2 = 0.f, a3 = 0.f;
    if (IN == 64) {
        int j = rs;
        for (; j + 4 <= re; j += 4) {
            int s0 = csr[j], s1 = csr[j + 1], s2 = csr[j + 2], s3 = csr[j + 3];
            a0 += h[(size_t)s0 * 64 + lane];
            a1 += h[(size_t)s1 * 64 + lane];
            a2 += h[(size_t)s2 * 64 + lane];
            a3 += h[(size_t)s3 * 64 + lane];
        }
        for (; j < re; ++j) a0 += h[(size_t)csr[j] * 64 + lane];
    } else {  // IN == 32: half-waves take alternating edges
        int f = lane & 31, half = lane >> 5;
        int j = rs + half;
        for (; j + 4 <= re; j += 4) {
            int s0 = csr[j], s1 = csr[j + 2];
            a0 += h[(size_t)s0 * 32 + f];
            a1 += h[(size_t)s1 * 32 + f];
        }
        for (; j < re; j += 2) a0 += h[(size_t)csr[j] * 32 + f];
    }
    float acc = (a0 + a1) + (a2 + a3);
    if (IN == 32) acc += __shfl_down(acc, 32);   // lanes 0..31 hold the full sum

    __syncthreads();   // Wt/bs staged; all lanes reach this (no early exits)

    if (IN == 64) aggS[wave][lane] = acc;
    else if (lane < 32) aggS[wave][lane] = acc;
    // intra-wave LDS write->read: compiler inserts lgkmcnt wait; no barrier needed

    float o_acc = 0.f;
#pragma unroll
    for (int k = 0; k < IN; ++k)
        o_acc = fmaf(aggS[wave][k], Wt[k * 65 + lane], o_acc);

    float nv = nrm[node];
    o_acc = o_acc * nv + bs[lane];
    if (ACT == 1) o_acc = fmaxf(o_acc, 0.f);
    if (ACT == 2) o_acc = 1.f / (1.f + expf(-o_acc));
    if (SCALE) o_acc *= nv;

    if (DUAL) {
        if (lane < 32) out [(size_t)node * 32 + lane]        = o_acc;
        else           out2[(size_t)node * 32 + (lane - 32)] = o_acc;
    } else {
        out[(size_t)node * 64 + lane] = o_acc;
    }
}

extern "C" void kernel_launch(void* const* d_in, const int* in_sizes, int n_in,
                              void* d_out, int out_size, void* d_ws, size_t ws_size,
                              hipStream_t stream) {
    const float* x    = (const float*)d_in[0];
    const int*   esrc = (const int*)d_in[1];
    const int*   edst = (const int*)d_in[2];
    const float* eps  = (const float*)d_in[3];
    const float* W1  = (const float*)d_in[4];  const float* b1  = (const float*)d_in[5];
    const float* W2  = (const float*)d_in[6];  const float* b2  = (const float*)d_in[7];
    const float* W31 = (const float*)d_in[8];  const float* b31 = (const float*)d_in[9];
    const float* W32 = (const float*)d_in[10]; const float* b32 = (const float*)d_in[11];
    const float* W4  = (const float*)d_in[12]; const float* b4  = (const float*)d_in[13];
    const float* W5  = (const float*)d_in[14]; const float* b5  = (const float*)d_in[15];
    const float* W6  = (const float*)d_in[16]; const float* b6  = (const float*)d_in[17];

    float* outp  = (float*)d_out;
    float* recon = outp;                        // N*64
    float* mu    = outp + (size_t)NN * 64;      // N*32
    float* lv    = mu   + (size_t)NN * 32;      // N*32

    int*   deg       = (int*)d_ws;              // N
    int*   incl      = deg + NN;                // N
    int*   bsums     = incl + NN;               // 512
    int*   row_start = bsums + 512;             // N+1
    int*   cursor    = row_start + NN + 1;      // N
    int*   csr       = cursor + NN;             // E
    float* nrm       = (float*)(csr + NE);      // N
    float* hA        = nrm + NN;                // N*64
    float* hB        = hA + (size_t)NN * 64;    // N*64

    const int SB = 256;
    const int egrid = (NE + SB - 1) / SB;
    const int ngrid = (NN + SB - 1) / SB;
    const int fgrid = NN / 4;                   // 25000, one wave per node

    // ---- CSR build + norm (once per call) ----
    hipMemsetAsync(deg, 0, (size_t)NN * sizeof(int), stream);
    degree_int_kernel<<<egrid, SB, 0, stream>>>(edst, deg, NE);
    norm_from_deg_kernel<<<ngrid, SB, 0, stream>>>(deg, nrm, NN);
    block_scan_kernel<<<NB_SCAN, 256, 0, stream>>>(deg, incl, bsums, NN);
    scan_sums_kernel<<<1, 512, 0, stream>>>(bsums, NB_SCAN);
    finalize_scan_kernel<<<ngrid, SB, 0, stream>>>(incl, deg, bsums, row_start, cursor, NN, NE);
    fill_csr_kernel<<<egrid, SB, 0, stream>>>(esrc, edst, cursor, csr, NE);

    // ---- pre-scale input ----
    scale_x_kernel<<<(NN * 64 + SB - 1) / SB, SB, 0, stream>>>(x, nrm, hA, NN * 64);

    // ---- layers ----
    // L1: hA -> hB (relu, scaled)
    gcn_fused_kernel<64, 1, true,  false><<<fgrid, 256, 0, stream>>>(hA, nrm, row_start, csr, W1, b1, nullptr, nullptr, hB, nullptr);
    // L2: hB -> hA (relu, scaled)
    gcn_fused_kernel<64, 1, true,  false><<<fgrid, 256, 0, stream>>>(hB, nrm, row_start, csr, W2, b2, nullptr, nullptr, hA, nullptr);
    // L3: hA -> mu, lv (ident, unscaled outputs)
    gcn_fused_kernel<64, 0, false, true ><<<fgrid, 256, 0, stream>>>(hA, nrm, row_start, csr, W31, b31, W32, b32, mu, lv);
    // z' (scaled) -> hB[0 : N*32]
    z_scaled_kernel<<<(NN * 32 + SB - 1) / SB, SB, 0, stream>>>(eps, mu, lv, nrm, hB, NN * 32);
    // L4: z'(32) -> hA (relu, scaled)
    gcn_fused_kernel<32, 1, true,  false><<<fgrid, 256, 0, stream>>>(hB, nrm, row_start, csr, W4, b4, nullptr, nullptr, hA, nullptr);
    // L5: hA -> hB (relu, scaled)
    gcn_fused_kernel<64, 1, true,  false><<<fgrid, 256, 0, stream>>>(hA, nrm, row_start, csr, W5, b5, nullptr, nullptr, hB, nullptr);
    // L6: hB -> recon (sigmoid, unscaled)
    gcn_fused_kernel<64, 2, false, false><<<fgrid, 256, 0, stream>>>(hB, nrm, row_start, csr, W6, b6, nullptr, nullptr, recon, nullptr);
}

// Round 3
// 839.971 us; speedup vs baseline: 3.7632x; 1.1634x over previous
//
#include <hip/hip_runtime.h>
#include <math.h>

#define NN 100000
#define NE 1600000
#define NB_SCAN ((NN + 255) / 256)   // 391 scan blocks

// ---------------- CSR build ----------------
__global__ void degree_int_kernel(const int* __restrict__ dst, int* __restrict__ deg, int E) {
    int e = blockIdx.x * blockDim.x + threadIdx.x;
    if (e < E) atomicAdd(&deg[dst[e]], 1);   // fire-and-forget (no return) -> fast
}

// per-256-block inclusive scan of deg -> incl, block sums -> bsums; also emits nrm
__global__ void block_scan_kernel(const int* __restrict__ deg, float* __restrict__ nrm,
                                  int* __restrict__ incl, int* __restrict__ bsums, int n) {
    __shared__ int s[256];
    int tid = threadIdx.x;
    int i = blockIdx.x * 256 + tid;
    int v = (i < n) ? deg[i] : 0;
    if (i < n) nrm[i] = rsqrtf(fmaxf((float)v, 1.0f));
    s[tid] = v;
    __syncthreads();
    for (int off = 1; off < 256; off <<= 1) {
        int t = (tid >= off) ? s[tid - off] : 0;
        __syncthreads();
        s[tid] += t;
        __syncthreads();
    }
    if (i < n) incl[i] = s[tid];
    if (tid == 255) bsums[blockIdx.x] = s[255];
}

__global__ void scan_sums_kernel(int* __restrict__ bsums, int nb) {
    __shared__ int s[512];
    int tid = threadIdx.x;
    s[tid] = (tid < nb) ? bsums[tid] : 0;
    __syncthreads();
    for (int off = 1; off < 512; off <<= 1) {
        int t = (tid >= off) ? s[tid - off] : 0;
        __syncthreads();
        s[tid] += t;
        __syncthreads();
    }
    if (tid < nb) bsums[tid] = s[tid];
}

__global__ void finalize_scan_kernel(const int* __restrict__ incl, const int* __restrict__ deg,
                                     const int* __restrict__ bsums,
                                     int* __restrict__ row_start, int* __restrict__ cursor,
                                     int n, int E) {
    int i = blockIdx.x * blockDim.x + threadIdx.x;
    if (i < n) {
        int b = i >> 8;
        int off = (b > 0) ? bsums[b - 1] : 0;
        int ex = off + incl[i] - deg[i];
        row_start[i] = ex;
        cursor[i] = ex;
        if (i == 0) row_start[n] = E;
    }
}

// 4 independent atomic round-trips in flight per thread (latency hiding).
__global__ void fill_csr_kernel(const int* __restrict__ src, const int* __restrict__ dst,
                                int* __restrict__ cursor, int* __restrict__ csr, int E) {
    const int stride = NE / 4;   // 400000
    int t = blockIdx.x * blockDim.x + threadIdx.x;
    if (t >= stride) return;
    int e0 = t, e1 = t + stride, e2 = t + 2 * stride, e3 = t + 3 * stride;
    int d0 = dst[e0], d1 = dst[e1], d2 = dst[e2], d3 = dst[e3];
    int s0 = src[e0], s1 = src[e1], s2 = src[e2], s3 = src[e3];
    int p0 = atomicAdd(&cursor[d0], 1);
    int p1 = atomicAdd(&cursor[d1], 1);
    int p2 = atomicAdd(&cursor[d2], 1);
    int p3 = atomicAdd(&cursor[d3], 1);
    csr[p0] = s0; csr[p1] = s1; csr[p2] = s2; csr[p3] = s3;
}

// x' = x * nrm[node], vectorized float4 (D=64 -> 16 float4 per node)
__global__ void scale_x4_kernel(const float4* __restrict__ x4, const float* __restrict__ nrm,
                                float4* __restrict__ xs4, int total4) {
    int i = blockIdx.x * blockDim.x + threadIdx.x;
    if (i < total4) {
        float nv = nrm[i >> 4];
        float4 v = x4[i];
        v.x *= nv; v.y *= nv; v.z *= nv; v.w *= nv;
        xs4[i] = v;
    }
}

// ---------------- fused gather(float4) + linear + act ----------------
// 256 threads = 4 waves; each wave processes 4 nodes CONCURRENTLY (MLP).
// Lane = (row_slot, f4): one dwordx4 load covers EPI edges per wave per node.
// h is PRE-SCALED by nrm[src]. out = act(nrm_dst*(agg@W^T)+b) [*nrm_dst if SCALE].
// DUAL: mu|lv heads + fused z' = (eps*exp(0.5 lv)+mu)*nrm -> zbuf.
template<int IN, int ACT, bool SCALE, bool DUAL>
__global__ __launch_bounds__(256) void gcn_fused_kernel(
        const float* __restrict__ h,
        const float* __restrict__ nrm,
        const int* __restrict__ row_start,
        const int* __restrict__ csr,
        const float* __restrict__ Wa, const float* __restrict__ ba,
        const float* __restrict__ Wb, const float* __restrict__ bb,
        float* __restrict__ out, float* __restrict__ out2,
        const float* __restrict__ eps, float* __restrict__ zbuf) {
    __shared__ float Wt[64 * 65];                    // [k][o] stride 65: 2-way (free) banks
    __shared__ float bs[64];
    __shared__ __align__(16) float aggS[4][4][IN];   // [wave][node_slot][IN]

    int tid = threadIdx.x;
    if (DUAL) {
        for (int i = tid; i < 32 * 64; i += 256) {   // Wa/Wb are [32][64]
            int o = i >> 6, k = i & 63;
            Wt[k * 65 + o]      = Wa[i];
            Wt[k * 65 + o + 32] = Wb[i];
        }
        if (tid < 32) { bs[tid] = ba[tid]; bs[tid + 32] = bb[tid]; }
    } else {
        for (int i = tid; i < 64 * IN; i += 256) {   // Wa is [64][IN]
            int o = i / IN, k = i % IN;
            Wt[k * 65 + o] = Wa[i];
        }
        if (tid < 64) bs[tid] = ba[tid];
    }
    __syncthreads();

    constexpr int RL  = IN / 4;        // lanes per row (16 or 8)
    constexpr int EPI = 64 / RL;       // edges per iteration (4 or 8)
    int wave = tid >> 6, lane = tid & 63;
    int row_slot = lane / RL;
    int f4 = lane % RL;
    int nodeBase = (blockIdx.x * 4 + wave) * 4;

    const float4* h4 = (const float4*)h;

    int rs[4], re[4];
#pragma unroll
    for (int i = 0; i < 4; ++i) {
        rs[i] = row_start[nodeBase + i];
        re[i] = row_start[nodeBase + i + 1];
    }
    int maxd = max(max(re[0] - rs[0], re[1] - rs[1]), max(re[2] - rs[2], re[3] - rs[3]));

    float4 acc[4];
#pragma unroll
    for (int i = 0; i < 4; ++i) acc[i] = make_float4(0.f, 0.f, 0.f, 0.f);

    for (int t = 0; t < maxd; t += EPI) {
#pragma unroll
        for (int i = 0; i < 4; ++i) {
            int jj = rs[i] + t + row_slot;
            bool ok = jj < re[i];
            int s = csr[ok ? jj : 0];
            float m = ok ? 1.f : 0.f;
            float4 v = h4[(size_t)s * RL + f4];
            acc[i].x = fmaf(m, v.x, acc[i].x);
            acc[i].y = fmaf(m, v.y, acc[i].y);
            acc[i].z = fmaf(m, v.z, acc[i].z);
            acc[i].w = fmaf(m, v.w, acc[i].w);
        }
    }

    // reduce across row_slots (xor masks RL..32)
#pragma unroll
    for (int i = 0; i < 4; ++i) {
        for (int o = RL; o < 64; o <<= 1) {
            acc[i].x += __shfl_xor(acc[i].x, o);
            acc[i].y += __shfl_xor(acc[i].y, o);
            acc[i].z += __shfl_xor(acc[i].z, o);
            acc[i].w += __shfl_xor(acc[i].w, o);
        }
    }

    if (row_slot == 0) {
#pragma unroll
        for (int i = 0; i < 4; ++i)
            ((float4*)aggS[wave][i])[f4] = acc[i];
    }
    // intra-wave LDS write->read ordered in program order; compiler inserts lgkmcnt

#pragma unroll
    for (int i = 0; i < 4; ++i) {
        int node = nodeBase + i;
        float oa = 0.f;
#pragma unroll
        for (int k = 0; k < IN; ++k)
            oa = fmaf(aggS[wave][i][k], Wt[k * 65 + lane], oa);
        float nv = nrm[node];
        oa = oa * nv + bs[lane];
        if (ACT == 1) oa = fmaxf(oa, 0.f);
        if (ACT == 2) oa = 1.f / (1.f + expf(-oa));
        if (SCALE) oa *= nv;

        if (DUAL) {
            if (lane < 32) out [(size_t)node * 32 + lane]        = oa;
            else           out2[(size_t)node * 32 + (lane - 32)] = oa;
            float lv_v = __shfl(oa, (lane + 32) & 63);   // lanes<32 receive lv
            if (lane < 32) {
                float e = eps[(size_t)node * 32 + lane];
                zbuf[(size_t)node * 32 + lane] = (e * expf(0.5f * lv_v) + oa) * nv;
            }
        } else {
            out[(size_t)node * 64 + lane] = oa;
        }
    }
}

extern "C" void kernel_launch(void* const* d_in, const int* in_sizes, int n_in,
                              void* d_out, int out_size, void* d_ws, size_t ws_size,
                              hipStream_t stream) {
    const float* x    = (const float*)d_in[0];
    const int*   esrc = (const int*)d_in[1];
    const int*   edst = (const int*)d_in[2];
    const float* eps  = (const float*)d_in[3];
    const float* W1  = (const float*)d_in[4];  const float* b1  = (const float*)d_in[5];
    const float* W2  = (const float*)d_in[6];  const float* b2  = (const float*)d_in[7];
    const float* W31 = (const float*)d_in[8];  const float* b31 = (const float*)d_in[9];
    const float* W32 = (const float*)d_in[10]; const float* b32 = (const float*)d_in[11];
    const float* W4  = (const float*)d_in[12]; const float* b4  = (const float*)d_in[13];
    const float* W5  = (const float*)d_in[14]; const float* b5  = (const float*)d_in[15];
    const float* W6  = (const float*)d_in[16]; const float* b6  = (const float*)d_in[17];

    float* outp  = (float*)d_out;
    float* recon = outp;                        // N*64
    float* mu    = outp + (size_t)NN * 64;      // N*32
    float* lv    = mu   + (size_t)NN * 32;      // N*32

    int*   deg       = (int*)d_ws;              // N
    int*   incl      = deg + NN;                // N
    int*   bsums     = incl + NN;               // 512
    int*   row_start = bsums + 512;             // N+1
    int*   cursor    = row_start + NN + 1;      // N
    int*   pad       = cursor + NN;             // 3 ints -> 16B-align hA/hB
    int*   csr       = pad + 3;                 // E
    float* nrm       = (float*)(csr + NE);      // N
    float* hA        = nrm + NN;                // N*64  (16B aligned)
    float* hB        = hA + (size_t)NN * 64;    // N*64  (16B aligned)

    const int SB = 256;
    const int egrid = (NE + SB - 1) / SB;
    const int ngrid = (NN + SB - 1) / SB;
    const int fgrid = NN / 16;                  // 6250: 4 waves x 4 nodes per block

    // ---- CSR build + norm ----
    hipMemsetAsync(deg, 0, (size_t)NN * sizeof(int), stream);
    degree_int_kernel<<<egrid, SB, 0, stream>>>(edst, deg, NE);
    block_scan_kernel<<<NB_SCAN, 256, 0, stream>>>(deg, nrm, incl, bsums, NN);
    scan_sums_kernel<<<1, 512, 0, stream>>>(bsums, NB_SCAN);
    finalize_scan_kernel<<<ngrid, SB, 0, stream>>>(incl, deg, bsums, row_start, cursor, NN, NE);
    fill_csr_kernel<<<(NE / 4 + SB - 1) / SB, SB, 0, stream>>>(esrc, edst, cursor, csr, NE);

    // ---- pre-scale input ----
    scale_x4_kernel<<<(NN * 16 + SB - 1) / SB, SB, 0, stream>>>((const float4*)x, nrm, (float4*)hA, NN * 16);

    // ---- layers ----
    gcn_fused_kernel<64, 1, true,  false><<<fgrid, 256, 0, stream>>>(hA, nrm, row_start, csr, W1,  b1,  nullptr, nullptr, hB,    nullptr, nullptr, nullptr);
    gcn_fused_kernel<64, 1, true,  false><<<fgrid, 256, 0, stream>>>(hB, nrm, row_start, csr, W2,  b2,  nullptr, nullptr, hA,    nullptr, nullptr, nullptr);
    // L3 dual: mu/lv to d_out, fused z' -> hB[0:N*32]
    gcn_fused_kernel<64, 0, false, true ><<<fgrid, 256, 0, stream>>>(hA, nrm, row_start, csr, W31, b31, W32,     b32,     mu,    lv,      eps,     hB);
    gcn_fused_kernel<32, 1, true,  false><<<fgrid, 256, 0, stream>>>(hB, nrm, row_start, csr, W4,  b4,  nullptr, nullptr, hA,    nullptr, nullptr, nullptr);
    gcn_fused_kernel<64, 1, true,  false><<<fgrid, 256, 0, stream>>>(hA, nrm, row_start, csr, W5,  b5,  nullptr, nullptr, hB,    nullptr, nullptr, nullptr);
    gcn_fused_kernel<64, 2, false, false><<<fgrid, 256, 0, stream>>>(hB, nrm, row_start, csr, W6,  b6,  nullptr, nullptr, recon, nullptr, nullptr, nullptr);
}